// Round 4
// baseline (1922.650 us; speedup 1.0000x reference)
//
#include <hip/hip_runtime.h>
#include <hip/hip_bf16.h>

typedef __hip_bfloat16 bf16;

#define Hh 160
#define Wd 160
#define HWp (Hh*Wd)       // 25600
#define Bn 2
#define Cc 64
#define NPIX (Bn*HWp)     // 51200
#define SCL 0.07905694150420949f   // 1/sqrt(160)
#define TWO_PI_160 0.039269908169872414f  // 2*pi/160

static __device__ __forceinline__ float b2f(bf16 x) { return __bfloat162float(x); }
static __device__ __forceinline__ bf16 f2b(float f) { return __float2bfloat16(f); }
static __device__ __forceinline__ float bfu(unsigned short u) {
  union { unsigned int i; float f; } z; z.i = ((unsigned int)u) << 16; return z.f;
}
static __device__ __forceinline__ unsigned short f2bu(float f) {
  union { bf16 h; unsigned short u; } z; z.h = __float2bfloat16(f); return z.u;
}

// ---------------- LayerNorm over channel dim (per pixel), fp32 in -> bf16 out ----------------
__global__ void k_ln(const float* __restrict__ in, const float* __restrict__ w,
                     const float* __restrict__ bb, bf16* __restrict__ out) {
  int idx = blockIdx.x * 256 + threadIdx.x;   // grid covers exactly NPIX
  int b = idx / HWp, p = idx - b * HWp;
  const float* src = in + (size_t)b * Cc * HWp + p;
  float s = 0.f, s2 = 0.f;
  for (int c = 0; c < Cc; c++) { float v = src[(size_t)c * HWp]; s += v; s2 += v * v; }
  float mu = s * (1.f / 64.f);
  float var = s2 * (1.f / 64.f) - mu * mu;
  float rs = rsqrtf(fmaxf(var, 0.f) + 1e-6f);
  bf16* dst = out + (size_t)b * Cc * HWp + p;
  for (int c = 0; c < Cc; c++) {
    float v = src[(size_t)c * HWp];
    dst[(size_t)c * HWp] = f2b((v - mu) * rs * w[c] + bb[c]);
  }
}

// ---------------- mean over HW per (b,c) plane (bf16 in) ----------------
__global__ void k_meanhw(const bf16* __restrict__ in, float* __restrict__ out) {
  int bc = blockIdx.x;
  const bf16* src = in + (size_t)bc * HWp;
  int t = threadIdx.x;
  float s = 0.f;
  for (int i = t; i < HWp; i += 256) s += b2f(src[i]);
  __shared__ float sm[256];
  sm[t] = s; __syncthreads();
  for (int off = 128; off; off >>= 1) { if (t < off) sm[t] += sm[t + off]; __syncthreads(); }
  if (t == 0) out[bc] = sm[0] * (1.f / HWp);
}

// ---------------- small matvec: out[b,o] = (addone) + W[o,:]·xin[b,:] + bias[o] ----------------
__global__ void k_small_mv(const float* __restrict__ xin, const float* __restrict__ w,
                           const float* __restrict__ bias, float* __restrict__ out, int addone) {
  int t = threadIdx.x;              // 128 threads
  int b = t >> 6, o = t & 63;
  float acc = bias[o];
  for (int k = 0; k < 64; k++) acc += w[o * 64 + k] * xin[b * 64 + k];
  out[t] = addone ? (1.f + acc) : acc;
}

// ---------------- generic 1x1 conv, bf16 ws in/out, fp32 weights ----------------
__global__ void k_conv1x1(const bf16* __restrict__ in, const float* __restrict__ w,
                          const float* __restrict__ bias, bf16* __restrict__ out,
                          int Cin, int Cout) {
  int p = blockIdx.x * 64 + threadIdx.x;
  int o = blockIdx.y * 4 + threadIdx.y;
  int b = blockIdx.z;
  float acc = bias[o];
  const bf16* src = in + (size_t)b * Cin * HWp + p;
  const float* wr = w + (size_t)o * Cin;
  for (int k = 0; k < Cin; k++) acc += wr[k] * b2f(src[(size_t)k * HWp]);
  out[((size_t)b * Cout + o) * HWp + p] = f2b(acc);
}

// ---------------- c11b: grouped 5x5 conv, groups=16 (4ch/group), pad 2 ----------------
__global__ void k_c11b(const bf16* __restrict__ in, const float* __restrict__ w,
                       const float* __restrict__ bias, bf16* __restrict__ out) {
  int p = blockIdx.x * 64 + threadIdx.x;
  int o = blockIdx.y * 4 + threadIdx.y;
  int b = blockIdx.z;
  int h = p / Wd, x = p - h * Wd;
  int gb = (o >> 2) << 2;
  float acc = bias[o];
  for (int ci = 0; ci < 4; ci++) {
    const bf16* src = in + ((size_t)b * Cc + gb + ci) * HWp;
    for (int ki = 0; ki < 5; ki++) {
      int hh = h + ki - 2; if ((unsigned)hh >= Hh) continue;
      for (int kj = 0; kj < 5; kj++) {
        int ww = x + kj - 2; if ((unsigned)ww >= Wd) continue;
        acc += w[((o * 4 + ci) * 5 + ki) * 5 + kj] * b2f(src[hh * Wd + ww]);
      }
    }
  }
  out[((size_t)b * Cc + o) * HWp + p] = f2b(acc);
}

// ---------------- c2a: grouped 3x3, 64->32, groups=32 (2 in-ch/group), pad 1 ----------------
__global__ void k_c2a(const bf16* __restrict__ in, const float* __restrict__ w,
                      const float* __restrict__ bias, bf16* __restrict__ out) {
  int p = blockIdx.x * 64 + threadIdx.x;
  int o = blockIdx.y * 4 + threadIdx.y;   // 0..31
  int b = blockIdx.z;
  int h = p / Wd, x = p - h * Wd;
  float acc = bias[o];
  for (int ci = 0; ci < 2; ci++) {
    const bf16* src = in + ((size_t)b * Cc + o * 2 + ci) * HWp;
    for (int ki = 0; ki < 3; ki++) {
      int hh = h + ki - 1; if ((unsigned)hh >= Hh) continue;
      for (int kj = 0; kj < 3; kj++) {
        int ww = x + kj - 1; if ((unsigned)ww >= Wd) continue;
        acc += w[((o * 2 + ci) * 3 + ki) * 3 + kj] * b2f(src[hh * Wd + ww]);
      }
    }
  }
  out[((size_t)b * 32 + o) * HWp + p] = f2b(acc);
}

// ---------------- att = c2c(gate(g))*attgamma + c211(x) ----------------
__global__ void k_att(const bf16* __restrict__ g, const bf16* __restrict__ x,
                      const float* __restrict__ c2cw, const float* __restrict__ c2cb,
                      const float* __restrict__ c211w, const float* __restrict__ c211b,
                      const float* __restrict__ attg, bf16* __restrict__ att) {
  int p = blockIdx.x * 64 + threadIdx.x;
  int s = blockIdx.y * 4 + threadIdx.y;   // 0..31
  int b = blockIdx.z;
  float a1 = c2cb[s];
  const bf16* gs = g + (size_t)b * 32 * HWp + p;
  for (int k = 0; k < 16; k++)
    a1 += c2cw[s * 16 + k] * b2f(gs[(size_t)k * HWp]) * b2f(gs[(size_t)(16 + k) * HWp]);
  float acc = a1 * attg[s] + c211b[s];
  const bf16* xs = x + (size_t)b * Cc * HWp + p;
  for (int c = 0; c < Cc; c++) acc += c211w[s * 64 + c] * b2f(xs[(size_t)c * HWp]);
  att[((size_t)b * 32 + s) * HWp + p] = f2b(acc);
}

// ---------------- depthwise 3x3, pad 1 ----------------
__global__ void k_c21dw(const bf16* __restrict__ in, const float* __restrict__ w,
                        const float* __restrict__ bias, bf16* __restrict__ out) {
  int p = blockIdx.x * 64 + threadIdx.x;
  int c = blockIdx.y * 4 + threadIdx.y;
  int b = blockIdx.z;
  int h = p / Wd, x = p - h * Wd;
  float acc = bias[c];
  const bf16* src = in + ((size_t)b * Cc + c) * HWp;
  for (int ki = 0; ki < 3; ki++) {
    int hh = h + ki - 1; if ((unsigned)hh >= Hh) continue;
    for (int kj = 0; kj < 3; kj++) {
      int ww = x + kj - 1; if ((unsigned)ww >= Wd) continue;
      acc += w[c * 9 + ki * 3 + kj] * b2f(src[hh * Wd + ww]);
    }
  }
  out[((size_t)b * Cc + c) * HWp + p] = f2b(acc);
}

// ---------------- KBA fused: out = ((kba+bias)*ga1 + uf) * x1 * sca ----------------
// tile = 64 consecutive pixels of one row. thread: g=t&15 (group), pq=t>>4 (4 px each).
__global__ __launch_bounds__(256) void k_kba(
    const bf16* __restrict__ uf, const bf16* __restrict__ att,
    const bf16* __restrict__ x1, const float* __restrict__ scaV,
    const float* __restrict__ kbw, const float* __restrict__ kbb,
    const float* __restrict__ ga1, bf16* __restrict__ out) {
  __shared__ unsigned short patchL[64 * 3 * 66];  // bf16 [c][ki][col], col = w0-1 .. w0+64
  __shared__ float attL[64][33];
  __shared__ unsigned short kwL[4 * 2304];
  int b = blockIdx.z, h = blockIdx.y;
  int w0 = blockIdx.x * 64;
  int width = min(64, Wd - w0);
  int t = threadIdx.x;
  const unsigned short* uf_u = (const unsigned short*)uf;
  for (int i = t; i < 64 * 3 * 66; i += 256) {
    int c = i / 198, rem = i - c * 198;
    int r = rem / 66, col = rem - r * 66;
    int hh = h + r - 1, ww = w0 + col - 1;
    unsigned short v = 0;
    if ((unsigned)hh < Hh && (unsigned)ww < Wd)
      v = uf_u[((size_t)b * Cc + c) * HWp + hh * Wd + ww];
    patchL[i] = v;
  }
  for (int i = t; i < 64 * 32; i += 256) {
    int px = i & 63, s = i >> 6;
    float v = 0.f;
    if (px < width) v = b2f(att[((size_t)b * 32 + s) * HWp + h * Wd + w0 + px]);
    attL[px][s] = v;
  }
  int g = t & 15, pq = t >> 4;
  float acc[4][4];
  #pragma unroll
  for (int j = 0; j < 4; j++) for (int o = 0; o < 4; o++) acc[j][o] = 0.f;
  for (int sc = 0; sc < 8; sc++) {        // 4 sets per chunk
    __syncthreads();
    for (int i = t; i < 4 * 2304; i += 256) kwL[i] = f2bu(kbw[sc * 4 * 2304 + i]);
    __syncthreads();
    for (int si = 0; si < 4; si++) {
      int s = sc * 4 + si;
      float a0 = attL[4 * pq + 0][s], a1 = attL[4 * pq + 1][s];
      float a2 = attL[4 * pq + 2][s], a3 = attL[4 * pq + 3][s];
      const unsigned short* wrow = &kwL[si * 2304 + g * 144];  // + o*36 + ci*9+ki*3+kj
      #pragma unroll
      for (int ci = 0; ci < 4; ci++) {
        const unsigned short* prow = &patchL[(g * 4 + ci) * 198 + 4 * pq];
        #pragma unroll
        for (int ki = 0; ki < 3; ki++) {
          const unsigned short* pr = prow + ki * 66;
          #pragma unroll
          for (int kj = 0; kj < 3; kj++) {
            int wi = ci * 9 + ki * 3 + kj;
            float wv0 = bfu(wrow[0 * 36 + wi]);
            float wv1 = bfu(wrow[1 * 36 + wi]);
            float wv2 = bfu(wrow[2 * 36 + wi]);
            float wv3 = bfu(wrow[3 * 36 + wi]);
            float p0 = bfu(pr[kj + 0]) * a0;
            float p1 = bfu(pr[kj + 1]) * a1;
            float p2 = bfu(pr[kj + 2]) * a2;
            float p3 = bfu(pr[kj + 3]) * a3;
            acc[0][0] += p0 * wv0; acc[0][1] += p0 * wv1; acc[0][2] += p0 * wv2; acc[0][3] += p0 * wv3;
            acc[1][0] += p1 * wv0; acc[1][1] += p1 * wv1; acc[1][2] += p1 * wv2; acc[1][3] += p1 * wv3;
            acc[2][0] += p2 * wv0; acc[2][1] += p2 * wv1; acc[2][2] += p2 * wv2; acc[2][3] += p2 * wv3;
            acc[3][0] += p3 * wv0; acc[3][1] += p3 * wv1; acc[3][2] += p3 * wv2; acc[3][3] += p3 * wv3;
          }
        }
      }
    }
  }
  // bias = att @ kb_b
  float bias_[4][4];
  #pragma unroll
  for (int j = 0; j < 4; j++) for (int o = 0; o < 4; o++) bias_[j][o] = 0.f;
  for (int s = 0; s < 32; s++) {
    float kv[4];
    #pragma unroll
    for (int o = 0; o < 4; o++) kv[o] = kbb[s * 64 + g * 4 + o];
    #pragma unroll
    for (int j = 0; j < 4; j++) {
      float av = attL[4 * pq + j][s];
      #pragma unroll
      for (int o = 0; o < 4; o++) bias_[j][o] += av * kv[o];
    }
  }
  for (int j = 0; j < 4; j++) {
    int px = 4 * pq + j;
    if (px >= width) continue;
    int p = h * Wd + w0 + px;
    for (int o = 0; o < 4; o++) {
      int c = g * 4 + o;
      float kout = acc[j][o] + bias_[j][o];
      float ufc = bfu(patchL[c * 198 + 66 + px + 1]);   // center tap
      float xk = kout * ga1[c] + ufc;
      float xv = xk * b2f(x1[((size_t)b * Cc + c) * HWp + p]) * scaV[b * 64 + c];
      out[((size_t)b * Cc + c) * HWp + p] = f2b(xv);
    }
  }
}

// ---------------- c3 1x1 conv + residual: y = inp + (conv)*beta (fp32 out) ----------------
__global__ void k_c3y(const bf16* __restrict__ xprod, const float* __restrict__ w,
                      const float* __restrict__ bias, const float* __restrict__ beta,
                      const float* __restrict__ inp, float* __restrict__ y) {
  int p = blockIdx.x * 64 + threadIdx.x;
  int o = blockIdx.y * 4 + threadIdx.y;
  int b = blockIdx.z;
  float acc = bias[o];
  const bf16* src = xprod + (size_t)b * Cc * HWp + p;
  const float* wr = w + o * 64;
  for (int k = 0; k < 64; k++) acc += wr[k] * b2f(src[(size_t)k * HWp]);
  size_t oi = ((size_t)b * Cc + o) * HWp + p;
  y[oi] = inp[oi] + acc * beta[o];
}

// ---------------- LayerNorm, fp32 in (y in d_out) -> bf16 ws out ----------------
__global__ void k_ln2(const float* __restrict__ in, const float* __restrict__ w,
                      const float* __restrict__ bb, bf16* __restrict__ out) {
  int idx = blockIdx.x * 256 + threadIdx.x;
  int b = idx / HWp, p = idx - b * HWp;
  const float* src = in + (size_t)b * Cc * HWp + p;
  float s = 0.f, s2 = 0.f;
  for (int c = 0; c < Cc; c++) { float v = src[(size_t)c * HWp]; s += v; s2 += v * v; }
  float mu = s * (1.f / 64.f);
  float var = s2 * (1.f / 64.f) - mu * mu;
  float rs = rsqrtf(fmaxf(var, 0.f) + 1e-6f);
  bf16* dst = out + (size_t)b * Cc * HWp + p;
  for (int c = 0; c < Cc; c++) {
    float v = src[(size_t)c * HWp];
    dst[(size_t)c * HWp] = f2b((v - mu) * rs * w[c] + bb[c]);
  }
}

// ---------------- one DFT pass with transpose: out[c][a] = scale * sum_b in[a][b] e^{i*sgn*2pi*b*c/N}
__global__ __launch_bounds__(256) void k_cpass(
    const bf16* __restrict__ inr, const bf16* __restrict__ ini,
    bf16* __restrict__ outr, bf16* __restrict__ outi,
    float sgn, float scale,
    const float* __restrict__ sclr, const float* __restrict__ scli) {
  int plane = blockIdx.z;
  int a0 = blockIdx.x * 64, c0 = blockIdx.y * 64;
  __shared__ float Lr[32][65], Li[32][65], Lc[32][65], Ls[32][65];
  int t = threadIdx.x;
  int ta = t & 15, tc = t >> 4;
  float ar[4][4], ai[4][4];
  #pragma unroll
  for (int j = 0; j < 4; j++) for (int k = 0; k < 4; k++) { ar[j][k] = 0.f; ai[j][k] = 0.f; }
  const bf16* pr = inr + (size_t)plane * HWp;
  const bf16* pi = ini ? ini + (size_t)plane * HWp : nullptr;
  float srm = sclr ? sclr[plane] : 1.f;
  float sim = scli ? scli[plane] : 1.f;
  for (int b0 = 0; b0 < 160; b0 += 32) {
    __syncthreads();
    for (int i = t; i < 32 * 64; i += 256) {
      int bb = i & 31, aa = i >> 5;
      int a = a0 + aa;
      float vr = 0.f, vi = 0.f;
      if (a < 160) {
        vr = b2f(pr[a * 160 + b0 + bb]) * srm;
        if (pi) vi = b2f(pi[a * 160 + b0 + bb]) * sim;
      }
      Lr[bb][aa] = vr; Li[bb][aa] = vi;
    }
    for (int i = t; i < 32 * 64; i += 256) {
      int cc = i & 63, bb = i >> 6;
      int c = c0 + cc;
      float vc = 0.f, vs = 0.f;
      if (c < 160) {
        int m = ((b0 + bb) * c) % 160;
        float sv, cv;
        __sincosf((float)m * TWO_PI_160, &sv, &cv);
        vc = cv; vs = sv * sgn;
      }
      Lc[bb][cc] = vc; Ls[bb][cc] = vs;
    }
    __syncthreads();
    for (int bb = 0; bb < 32; bb++) {
      float xr[4], xi[4], cs[4], sn[4];
      #pragma unroll
      for (int j = 0; j < 4; j++) { xr[j] = Lr[bb][ta * 4 + j]; xi[j] = Li[bb][ta * 4 + j]; }
      #pragma unroll
      for (int k = 0; k < 4; k++) { cs[k] = Lc[bb][tc * 4 + k]; sn[k] = Ls[bb][tc * 4 + k]; }
      #pragma unroll
      for (int j = 0; j < 4; j++)
        #pragma unroll
        for (int k = 0; k < 4; k++) {
          ar[j][k] += xr[j] * cs[k] - xi[j] * sn[k];
          ai[j][k] += xr[j] * sn[k] + xi[j] * cs[k];
        }
    }
  }
  for (int k = 0; k < 4; k++) {
    int c = c0 + tc * 4 + k;
    if (c >= 160) continue;
    for (int j = 0; j < 4; j++) {
      int a = a0 + ta * 4 + j;
      if (a >= 160) continue;
      outr[(size_t)plane * HWp + c * 160 + a] = f2b(ar[j][k] * scale);
      outi[(size_t)plane * HWp + c * 160 + a] = f2b(ai[j][k] * scale);
    }
  }
}

// ---------------- final inverse pass, fused |.|, *gamma, += y (fp32 d_out) ----------------
__global__ __launch_bounds__(256) void k_cpass_final(
    const bf16* __restrict__ inr, const bf16* __restrict__ ini,
    float sgn, float scale,
    const float* __restrict__ gamma, float* __restrict__ dout) {
  int plane = blockIdx.z;
  int a0 = blockIdx.x * 64, c0 = blockIdx.y * 64;
  __shared__ float Lr[32][65], Li[32][65], Lc[32][65], Ls[32][65];
  int t = threadIdx.x;
  int ta = t & 15, tc = t >> 4;
  float ar[4][4], ai[4][4];
  #pragma unroll
  for (int j = 0; j < 4; j++) for (int k = 0; k < 4; k++) { ar[j][k] = 0.f; ai[j][k] = 0.f; }
  const bf16* pr = inr + (size_t)plane * HWp;
  const bf16* pi = ini + (size_t)plane * HWp;
  for (int b0 = 0; b0 < 160; b0 += 32) {
    __syncthreads();
    for (int i = t; i < 32 * 64; i += 256) {
      int bb = i & 31, aa = i >> 5;
      int a = a0 + aa;
      float vr = 0.f, vi = 0.f;
      if (a < 160) { vr = b2f(pr[a * 160 + b0 + bb]); vi = b2f(pi[a * 160 + b0 + bb]); }
      Lr[bb][aa] = vr; Li[bb][aa] = vi;
    }
    for (int i = t; i < 32 * 64; i += 256) {
      int cc = i & 63, bb = i >> 6;
      int c = c0 + cc;
      float vc = 0.f, vs = 0.f;
      if (c < 160) {
        int m = ((b0 + bb) * c) % 160;
        float sv, cv;
        __sincosf((float)m * TWO_PI_160, &sv, &cv);
        vc = cv; vs = sv * sgn;
      }
      Lc[bb][cc] = vc; Ls[bb][cc] = vs;
    }
    __syncthreads();
    for (int bb = 0; bb < 32; bb++) {
      float xr[4], xi[4], cs[4], sn[4];
      #pragma unroll
      for (int j = 0; j < 4; j++) { xr[j] = Lr[bb][ta * 4 + j]; xi[j] = Li[bb][ta * 4 + j]; }
      #pragma unroll
      for (int k = 0; k < 4; k++) { cs[k] = Lc[bb][tc * 4 + k]; sn[k] = Ls[bb][tc * 4 + k]; }
      #pragma unroll
      for (int j = 0; j < 4; j++)
        #pragma unroll
        for (int k = 0; k < 4; k++) {
          ar[j][k] += xr[j] * cs[k] - xi[j] * sn[k];
          ai[j][k] += xr[j] * sn[k] + xi[j] * cs[k];
        }
    }
  }
  int ch = plane & 63;
  float gm = gamma[ch];
  for (int k = 0; k < 4; k++) {
    int c = c0 + tc * 4 + k;          // = h
    if (c >= 160) continue;
    for (int j = 0; j < 4; j++) {
      int a = a0 + ta * 4 + j;        // = w
      if (a >= 160) continue;
      float rr = ar[j][k] * scale, ii = ai[j][k] * scale;
      float z = sqrtf(rr * rr + ii * ii);
      size_t oi = (size_t)plane * HWp + c * 160 + a;
      dout[oi] = dout[oi] + z * gm;   // dout currently holds y
    }
  }
}

// ---------------- fc1 (128->256) + simple_gate ----------------
__global__ void k_fc1gate(const bf16* __restrict__ Fr, const bf16* __restrict__ Fi,
                          const float* __restrict__ w, const float* __restrict__ bias,
                          bf16* __restrict__ G1, bf16* __restrict__ G2) {
  int p = blockIdx.x * 64 + threadIdx.x;
  int o = blockIdx.y * 4 + threadIdx.y;   // 0..127
  int b = blockIdx.z;
  float acc1 = bias[o], acc2 = bias[o + 128];
  const float* w1 = w + (size_t)o * 128;
  const float* w2 = w + (size_t)(o + 128) * 128;
  const bf16* fr = Fr + (size_t)b * Cc * HWp + p;
  const bf16* fi = Fi + (size_t)b * Cc * HWp + p;
  for (int k = 0; k < 64; k++) {
    float v = b2f(fr[(size_t)k * HWp]);
    acc1 += w1[k] * v; acc2 += w2[k] * v;
  }
  for (int k = 0; k < 64; k++) {
    float v = b2f(fi[(size_t)k * HWp]);
    acc1 += w1[64 + k] * v; acc2 += w2[64 + k] * v;
  }
  float gv = acc1 * acc2;
  if (o < 64) G1[((size_t)b * Cc + o) * HWp + p] = f2b(gv);
  else        G2[((size_t)b * Cc + o - 64) * HWp + p] = f2b(gv);
}

// ---------------- fc2 (128->128), split output into r / i planes ----------------
__global__ void k_fc2(const bf16* __restrict__ G1, const bf16* __restrict__ G2,
                      const float* __restrict__ w, const float* __restrict__ bias,
                      bf16* __restrict__ Or, bf16* __restrict__ Oi) {
  int p = blockIdx.x * 64 + threadIdx.x;
  int o = blockIdx.y * 4 + threadIdx.y;   // 0..127
  int b = blockIdx.z;
  float acc = bias[o];
  const float* wr = w + (size_t)o * 128;
  const bf16* g1 = G1 + (size_t)b * Cc * HWp + p;
  const bf16* g2 = G2 + (size_t)b * Cc * HWp + p;
  for (int k = 0; k < 64; k++) acc += wr[k] * b2f(g1[(size_t)k * HWp]);
  for (int k = 0; k < 64; k++) acc += wr[64 + k] * b2f(g2[(size_t)k * HWp]);
  if (o < 64) Or[((size_t)b * Cc + o) * HWp + p] = f2b(acc);
  else        Oi[((size_t)b * Cc + o - 64) * HWp + p] = f2b(acc);
}

extern "C" void kernel_launch(void* const* d_in, const int* in_sizes, int n_in,
                              void* d_out, int out_size, void* d_ws, size_t ws_size,
                              hipStream_t stream) {
  const float* inp   = (const float*)d_in[0];
  const float* n1w   = (const float*)d_in[1];
  const float* n1b   = (const float*)d_in[2];
  const float* n2w   = (const float*)d_in[3];
  const float* n2b   = (const float*)d_in[4];
  const float* scaw  = (const float*)d_in[5];
  const float* scab  = (const float*)d_in[6];
  const float* c11aw = (const float*)d_in[7];
  const float* c11ab = (const float*)d_in[8];
  const float* c11bw = (const float*)d_in[9];
  const float* c11bb = (const float*)d_in[10];
  const float* c1w   = (const float*)d_in[11];
  const float* c1b   = (const float*)d_in[12];
  const float* c21w  = (const float*)d_in[13];
  const float* c21b  = (const float*)d_in[14];
  const float* c2aw  = (const float*)d_in[15];
  const float* c2ab  = (const float*)d_in[16];
  const float* c2cw  = (const float*)d_in[17];
  const float* c2cb  = (const float*)d_in[18];
  const float* c211w = (const float*)d_in[19];
  const float* c211b = (const float*)d_in[20];
  const float* c3w   = (const float*)d_in[21];
  const float* c3b   = (const float*)d_in[22];
  const float* kbw   = (const float*)d_in[23];
  const float* kbb   = (const float*)d_in[24];
  const float* ga1   = (const float*)d_in[25];
  const float* attg  = (const float*)d_in[26];
  const float* beta  = (const float*)d_in[27];
  const float* gamma = (const float*)d_in[28];
  const float* fc1w  = (const float*)d_in[29];
  const float* fc1b  = (const float*)d_in[30];
  const float* fc2w  = (const float*)d_in[31];
  const float* fc2b  = (const float*)d_in[32];
  const float* fscaw = (const float*)d_in[33];
  const float* fscab = (const float*)d_in[34];

  const size_t S = (size_t)Bn * Cc * HWp;   // 3,276,800 elements per slot
  bf16* A  = (bf16*)d_ws;                   // 4 bf16 slots = 26.2 MB total
  bf16* Bs = A + S;
  bf16* Cs = A + 2 * S;
  bf16* Ds = A + 3 * S;
  float* smalls = (float*)(A + 4 * S);      // 768 floats = 3 KB
  float* xm   = smalls;
  float* scaV = smalls + 128;
  float* rmv  = smalls + 256;
  float* imv  = smalls + 384;
  float* sra  = smalls + 512;
  float* sia  = smalls + 640;
  bf16* gbuf = Bs;            // [B,32,HW] (first half of Bs)
  bf16* attb = Bs + S / 2;    // [B,32,HW] (second half of Bs)
  float* yb  = (float*)d_out; // y lives in d_out (fp32)

  dim3 blk(64, 4, 1);

  k_ln<<<dim3(200), dim3(256), 0, stream>>>(inp, n1w, n1b, A);          // A = x
  k_meanhw<<<dim3(128), dim3(256), 0, stream>>>(A, xm);
  k_small_mv<<<dim3(1), dim3(128), 0, stream>>>(xm, scaw, scab, scaV, 0);
  k_conv1x1<<<dim3(400, 16, Bn), blk, 0, stream>>>(A, c11aw, c11ab, Bs, 64, 64);   // B = t1
  k_c11b<<<dim3(400, 16, Bn), blk, 0, stream>>>(Bs, c11bw, c11bb, Cs);             // C = x1 (B dead)
  k_c2a<<<dim3(400, 8, Bn), blk, 0, stream>>>(A, c2aw, c2ab, gbuf);                // B.lo = g
  k_att<<<dim3(400, 8, Bn), blk, 0, stream>>>(gbuf, A, c2cw, c2cb, c211w, c211b, attg, attb); // B.hi = att
  k_conv1x1<<<dim3(400, 16, Bn), blk, 0, stream>>>(A, c1w, c1b, Ds, 64, 64);       // D = t2 (A dead after)
  k_c21dw<<<dim3(400, 16, Bn), blk, 0, stream>>>(Ds, c21w, c21b, A);               // A = uf
  k_kba<<<dim3(3, 160, Bn), dim3(256), 0, stream>>>(A, attb, Cs, scaV, kbw, kbb, ga1, Ds); // D = xprod
  k_c3y<<<dim3(400, 16, Bn), blk, 0, stream>>>(Ds, c3w, c3b, beta, inp, yb);       // d_out = y (fp32)
  k_ln2<<<dim3(200), dim3(256), 0, stream>>>(yb, n2w, n2b, A);                     // A = X
  // forward FFT2: pass over W ([h][w] -> [u][h]), then over H ([u][h] -> [v][u])
  k_cpass<<<dim3(3, 3, Bn * Cc), dim3(256), 0, stream>>>(A, (const bf16*)nullptr, Bs, Cs, -1.f, SCL, nullptr, nullptr); // B,C = F1 (A dead)
  k_cpass<<<dim3(3, 3, Bn * Cc), dim3(256), 0, stream>>>(Bs, Cs, Ds, A, -1.f, SCL, nullptr, nullptr);                   // D,A = F2
  k_fc1gate<<<dim3(400, 32, Bn), blk, 0, stream>>>(Ds, A, fc1w, fc1b, Bs, Cs);     // B,C = gated
  k_fc2<<<dim3(400, 32, Bn), blk, 0, stream>>>(Bs, Cs, fc2w, fc2b, Ds, A);         // D = r, A = i
  k_meanhw<<<dim3(128), dim3(256), 0, stream>>>(Ds, rmv);
  k_meanhw<<<dim3(128), dim3(256), 0, stream>>>(A, imv);
  k_small_mv<<<dim3(1), dim3(128), 0, stream>>>(rmv, fscaw, fscab, sra, 1);
  k_small_mv<<<dim3(1), dim3(128), 0, stream>>>(imv, fscaw, fscab, sia, 1);
  // inverse FFT2 with per-plane (1+ra)/(1+ia) scaling fused into first pass
  k_cpass<<<dim3(3, 3, Bn * Cc), dim3(256), 0, stream>>>(Ds, A, Bs, Cs, 1.f, SCL, sra, sia);  // B,C
  k_cpass_final<<<dim3(3, 3, Bn * Cc), dim3(256), 0, stream>>>(Bs, Cs, 1.f, SCL, gamma, yb);  // d_out = y + |z|*gamma
}